// Round 8
// baseline (227.435 us; speedup 1.0000x reference)
//
#include <hip/hip_runtime.h>

// ---------------------------------------------------------------------------
// CoupledFEMSolver — fused gather assembly v3.
//   * index_build: per-partition LDS hist -> block scan -> TRANSPOSED prefix
//     P2[node][partition] (gather reads coalesced) -> partition-contiguous
//     entry lists.
//   * fused_gather (interleaved solid/fluid blocks):
//       - prologue: coalesced P2 rows; Qb wave-scan; O(1) visit->partition
//         table (pvt, reuses claim buffer); fully prefetched visits.
//       - MULTI-CLAIM loop: claim all <=6 pending columns per round; winners
//         recompute values (VALU idle) and plain-RMW; double-buffered live
//         flag instead of __syncthreads_count. Diagonal in registers.
//       - plane-major LDS accumulators -> contiguous b128 stores; M_s inline.
//
// Geometry per tet (double math; K entries ~ 1/det reach ~1e14):
//   det = r1.(r2 x r3); g1=(r2xr3)/det, g2=(r3xr1)/det, g3=(r1xr2)/det,
//   g0=-(g1+g2+g3); vol=|det|/6
// Fluid:  K_e[a][b] = vol*(ga.gb); M_e[a][b] = vol*(a==b ? .3 : .1)
// Solid:  K block (a,b) entry (i,j) =
//   vol*(lam*ga_i*gb_j + mu*ga_j*gb_i + (i==j)*mu*(ga.gb));
//   M_s diagonal only: rho*vol/4 per dof.
// ---------------------------------------------------------------------------

#define G_PART 256

__device__ __forceinline__ float sel4(float x0, float x1, float x2, float x3, int a) {
    float r = x0;
    r = (a == 1) ? x1 : r;
    r = (a == 2) ? x2 : r;
    r = (a == 3) ? x3 : r;
    return r;
}
__device__ __forceinline__ int sel4i(int x0, int x1, int x2, int x3, int a) {
    int r = x0;
    r = (a == 1) ? x1 : r;
    r = (a == 2) ? x2 : r;
    r = (a == 3) ? x3 : r;
    return r;
}

__device__ __forceinline__ float wave_reduce(float v) {
#pragma unroll
    for (int m = 1; m < 64; m <<= 1) v += __shfl_xor(v, m, 64);
    return v;
}

// double-precision tet geometry -> f32 gradients g1..g3 and volume
__device__ __forceinline__ void tet_geom_f(const float* __restrict__ nodes,
                                           int n0, int n1, int n2, int n3_,
                                           float& gx1, float& gy1, float& gz1,
                                           float& gx2, float& gy2, float& gz2,
                                           float& gx3, float& gy3, float& gz3,
                                           float& volf)
{
    const float* q0 = nodes + 3ll * n0;
    const float* q1 = nodes + 3ll * n1;
    const float* q2 = nodes + 3ll * n2;
    const float* q3 = nodes + 3ll * n3_;
    double p0x = q0[0], p0y = q0[1], p0z = q0[2];
    double r1x = (double)q1[0] - p0x, r1y = (double)q1[1] - p0y, r1z = (double)q1[2] - p0z;
    double r2x = (double)q2[0] - p0x, r2y = (double)q2[1] - p0y, r2z = (double)q2[2] - p0z;
    double r3x = (double)q3[0] - p0x, r3y = (double)q3[1] - p0y, r3z = (double)q3[2] - p0z;
    double c23x = r2y*r3z - r2z*r3y, c23y = r2z*r3x - r2x*r3z, c23z = r2x*r3y - r2y*r3x;
    double det = r1x*c23x + r1y*c23y + r1z*c23z;
    double inv = 1.0 / det;
    double c31x = r3y*r1z - r3z*r1y, c31y = r3z*r1x - r3x*r1z, c31z = r3x*r1y - r3y*r1x;
    double c12x = r1y*r2z - r1z*r2y, c12y = r1z*r2x - r1x*r2z, c12z = r1x*r2y - r1y*r2x;
    gx1 = (float)(c23x*inv); gy1 = (float)(c23y*inv); gz1 = (float)(c23z*inv);
    gx2 = (float)(c31x*inv); gy2 = (float)(c31y*inv); gz2 = (float)(c31z*inv);
    gx3 = (float)(c12x*inv); gy3 = (float)(c12y*inv); gz3 = (float)(c12z*inv);
    volf = (float)(fabs(det) / 6.0);
}

// tail-only: 8-step bisection over Qb (rare rows with >1024 visits)
__device__ __forceinline__ int fetch_entry_bs(const int* __restrict__ ent,
                                              const int* __restrict__ Sb,
                                              const int* __restrict__ Qb,
                                              int chunk4, int v)
{
    int lo = 0, hi = 255;
#pragma unroll
    for (int it = 0; it < 8; ++it) {
        int mid = (lo + hi + 1) >> 1;
        bool ge = (Qb[mid] <= v);
        lo = ge ? mid : lo;
        hi = ge ? hi : mid - 1;
    }
    return ent[(size_t)lo * chunk4 + Sb[lo] + (v - Qb[lo])];
}

// named-register visit state (incl. precomputed off-diag columns k0..k2)
#define DECL_VISIT(P) \
    float P##gx0=0,P##gx1=0,P##gx2=0,P##gx3=0, P##gy0=0,P##gy1=0,P##gy2=0,P##gy3=0, \
          P##gz0=0,P##gz1=0,P##gz2=0,P##gz3=0, P##vol=0, P##ga0=0,P##ga1=0,P##ga2=0; \
    int P##a=0, P##k0=0, P##k1=0, P##k2=0;

#define LOAD_VISIT(P, packed_) do { \
    int e_ = (packed_) >> 2; P##a = (packed_) & 3; \
    int4 nd_ = elems4[e_]; \
    tet_geom_f(nodes, nd_.x, nd_.y, nd_.z, nd_.w, \
        P##gx1,P##gy1,P##gz1, P##gx2,P##gy2,P##gz2, P##gx3,P##gy3,P##gz3, P##vol); \
    P##gx0 = -(P##gx1+P##gx2+P##gx3); \
    P##gy0 = -(P##gy1+P##gy2+P##gy3); \
    P##gz0 = -(P##gz1+P##gz2+P##gz3); \
    P##ga0 = sel4(P##gx0,P##gx1,P##gx2,P##gx3,P##a); \
    P##ga1 = sel4(P##gy0,P##gy1,P##gy2,P##gy3,P##a); \
    P##ga2 = sel4(P##gz0,P##gz1,P##gz2,P##gz3,P##a); \
    P##k0 = sel4i(nd_.x, nd_.y, nd_.z, nd_.w, 0 + ((0 >= P##a) ? 1 : 0)); \
    P##k1 = sel4i(nd_.x, nd_.y, nd_.z, nd_.w, 1 + ((1 >= P##a) ? 1 : 0)); \
    P##k2 = sel4i(nd_.x, nd_.y, nd_.z, nd_.w, 2 + ((2 >= P##a) ? 1 : 0)); \
} while (0)

#define DIAG_S(P) do { \
    float lv_ = lam*P##vol, mv_ = mu*P##vol, lm_ = lv_+mv_; \
    float mgg_ = mv_*(P##ga0*P##ga0 + P##ga1*P##ga1 + P##ga2*P##ga2); \
    d00 += lm_*P##ga0*P##ga0 + mgg_; d01 += lm_*P##ga0*P##ga1;        d02 += lm_*P##ga0*P##ga2; \
    d10 += lm_*P##ga1*P##ga0;        d11 += lm_*P##ga1*P##ga1 + mgg_; d12 += lm_*P##ga1*P##ga2; \
    d20 += lm_*P##ga2*P##ga0;        d21 += lm_*P##ga2*P##ga1;        d22 += lm_*P##ga2*P##ga2 + mgg_; \
    vsum += P##vol; } while (0)

#define DIAG_F(P) do { \
    dK += P##vol*(P##ga0*P##ga0 + P##ga1*P##ga1 + P##ga2*P##ga2); \
    dM += P##vol*0.3f; } while (0)

// winner update, solid: recompute 9 values for slot K of visit P, plain RMW
#define WIN_S(P, K, BIT) \
    if ((slots & (BIT)) && claim[P##k##K] == (unsigned short)tid) { \
        int b_ = (K) + (((K) >= P##a) ? 1 : 0); \
        float gb0_ = sel4(P##gx0,P##gx1,P##gx2,P##gx3,b_); \
        float gb1_ = sel4(P##gy0,P##gy1,P##gy2,P##gy3,b_); \
        float gb2_ = sel4(P##gz0,P##gz1,P##gz2,P##gz3,b_); \
        float lv_ = lam*P##vol, mv_ = mu*P##vol; \
        float la0_=lv_*P##ga0, la1_=lv_*P##ga1, la2_=lv_*P##ga2; \
        float ma0_=mv_*P##ga0, ma1_=mv_*P##ga1, ma2_=mv_*P##ga2; \
        float mgg_ = mv_*(P##ga0*gb0_ + P##ga1*gb1_ + P##ga2*gb2_); \
        float* p0_ = val + 3*P##k##K; float* p1_ = p0_ + n3; float* p2_ = p1_ + n3; \
        p0_[0] += la0_*gb0_ + ma0_*gb0_ + mgg_; \
        p0_[1] += la0_*gb1_ + ma1_*gb0_; \
        p0_[2] += la0_*gb2_ + ma2_*gb0_; \
        p1_[0] += la1_*gb0_ + ma0_*gb1_; \
        p1_[1] += la1_*gb1_ + ma1_*gb1_ + mgg_; \
        p1_[2] += la1_*gb2_ + ma2_*gb1_; \
        p2_[0] += la2_*gb0_ + ma0_*gb2_; \
        p2_[1] += la2_*gb1_ + ma1_*gb2_; \
        p2_[2] += la2_*gb2_ + ma2_*gb2_ + mgg_; \
        slots &= ~(BIT); \
    }

// winner update, fluid
#define WIN_F(P, K, BIT) \
    if ((slots & (BIT)) && claim[P##k##K] == (unsigned short)tid) { \
        int b_ = (K) + (((K) >= P##a) ? 1 : 0); \
        float gb0_ = sel4(P##gx0,P##gx1,P##gx2,P##gx3,b_); \
        float gb1_ = sel4(P##gy0,P##gy1,P##gy2,P##gy3,b_); \
        float gb2_ = sel4(P##gz0,P##gz1,P##gz2,P##gz3,b_); \
        val[P##k##K]     += P##vol*(P##ga0*gb0_ + P##ga1*gb1_ + P##ga2*gb2_); \
        val[n + P##k##K] += P##vol*0.1f; \
        slots &= ~(BIT); \
    }

// ------------------- one-kernel partition-local index build ------------------
__global__ void __launch_bounds__(256)
index_build(const int4* __restrict__ fe, const int4* __restrict__ se,
            int* __restrict__ entF, int* __restrict__ entS,
            int* __restrict__ PF, int* __restrict__ PS,
            int nf, int ns, int n, int chunkF, int chunkS)
{
    extern __shared__ int h[];            // n + 256
    int* wsum = h + n;
    const bool solid = blockIdx.x >= G_PART;
    const int b = solid ? blockIdx.x - G_PART : blockIdx.x;
    const int4* elems = solid ? se : fe;
    const int nelem = solid ? ns : nf;
    const int chunk = solid ? chunkS : chunkF;
    int* P2 = solid ? PS : PF;            // layout: P2[node][partition]
    int* entries = (solid ? entS : entF) + (size_t)b * 4 * chunk;

    const int t = threadIdx.x;
    const int beg = b * chunk, end = min(nelem, beg + chunk);

    for (int i = t; i < n; i += 256) h[i] = 0;
    __syncthreads();
    for (int e = beg + t; e < end; e += 256) {
        int4 nd = elems[e];
        atomicAdd(&h[nd.x], 1);
        atomicAdd(&h[nd.y], 1);
        atomicAdd(&h[nd.z], 1);
        atomicAdd(&h[nd.w], 1);
    }
    __syncthreads();

    // block exclusive scan of h[0..n)
    const int cs = (n + 255) / 256;
    const int base = t * cs;
    int s = 0;
    for (int k = 0; k < cs; ++k) {
        int i = base + k;
        if (i < n) s += h[i];
    }
    wsum[t] = s;
    __syncthreads();
    for (int d = 1; d < 256; d <<= 1) {
        int v = (t >= d) ? wsum[t - d] : 0;
        __syncthreads();
        wsum[t] += v;
        __syncthreads();
    }
    int run = (t == 0) ? 0 : wsum[t - 1];
    for (int k = 0; k < cs; ++k) {
        int i = base + k;
        if (i < n) {
            int c = h[i]; h[i] = run;
            P2[(size_t)i * G_PART + b] = run;
            run += c;
        }
    }
    if (t == 255) P2[(size_t)n * G_PART + b] = wsum[255];
    __syncthreads();

    // place entries (h[] now holds cursors = prefix)
    for (int e = beg + t; e < end; e += 256) {
        int4 nd = elems[e];
        int p;
        p = atomicAdd(&h[nd.x], 1); entries[p] = e * 4 + 0;
        p = atomicAdd(&h[nd.y], 1); entries[p] = e * 4 + 1;
        p = atomicAdd(&h[nd.z], 1); entries[p] = e * 4 + 2;
        p = atomicAdd(&h[nd.w], 1); entries[p] = e * 4 + 3;
    }
}

// ------------------------------ fused gather --------------------------------
// interleaved: even bid -> solid row (bid>>1); odd bid -> fluid row (bid>>1)
__global__ void __launch_bounds__(512, 4)
fused_gather(const int* __restrict__ entF, const int* __restrict__ PF,
             const int* __restrict__ entS, const int* __restrict__ PS,
             const int4* __restrict__ fe, const int4* __restrict__ se,
             const float* __restrict__ nodes,
             float* __restrict__ Kf, float* __restrict__ Mf,
             float* __restrict__ Ks, float* __restrict__ Ms,
             const float* __restrict__ E_p, const float* __restrict__ nu_p,
             const float* __restrict__ rho_p, int n, int n3,
             int chunk4F, int chunk4S)
{
    extern __shared__ unsigned char smem[];
    const int tid = threadIdx.x;
    const int bid = blockIdx.x;
    const bool isSolid = (bid & 1) == 0;
    const int r = bid >> 1;

    if (isSolid) {
        // ================= solid =================
        const int4* elems4 = se;
        float* val = (float*)smem;                               // 9n (3 planes of n3)
        unsigned short* claim = (unsigned short*)(val + 9 * n);  // n  (pvt in prologue)
        int* Sb = (int*)(claim + n);                             // 256
        int* Qb = Sb + 256;                                      // 257
        float* dred = (float*)(Qb + 257);                        // 90
        int* flg = (int*)(dred + 90);                            // 2

        {
            float4* v = (float4*)val;
            int cnt = (9 * n) >> 2;
            for (int k = tid; k < cnt; k += 512) v[k] = make_float4(0.f,0.f,0.f,0.f);
        }
        if (tid < 256) {
            int s0 = PS[(size_t)r * G_PART + tid];
            int e0 = PS[(size_t)(r + 1) * G_PART + tid];
            Sb[tid] = s0;
            Qb[tid] = e0 - s0;     // counts; scanned below
        }
        if (tid == 0) { flg[0] = 0; flg[1] = 0; }
        __syncthreads();
        if (tid < 64) {
            int c0 = Qb[4*tid], c1 = Qb[4*tid+1], c2 = Qb[4*tid+2], c3 = Qb[4*tid+3];
            int s = c0 + c1 + c2 + c3;
            int x = s;
#pragma unroll
            for (int d = 1; d < 64; d <<= 1) {
                int y = __shfl_up(x, d, 64);
                if (tid >= d) x += y;
            }
            int ex = x - s;
            Qb[4*tid] = ex; Qb[4*tid+1] = ex + c0;
            Qb[4*tid+2] = ex + c0 + c1; Qb[4*tid+3] = ex + c0 + c1 + c2;
            if (tid == 63) Qb[256] = ex + s;
        }
        __syncthreads();
        const int T = Qb[256];
        const int pvLim = min(T, n);

        // O(1) visit->partition table (claim buffer as scratch, pre-loop)
        if (tid < 256) {
            int v0 = Qb[tid], v1 = min(Qb[tid + 1], pvLim);
            for (int v = v0; v < v1; ++v) claim[v] = (unsigned short)tid;
        }
        __syncthreads();

        float E = *E_p, nu = *nu_p, rho = *rho_p;
        float coeff = E / ((1.f + nu) * (1.f - 2.f * nu));
        float lam = coeff * nu;
        float mu  = coeff * (1.f - 2.f * nu) * 0.5f;

        float d00=0,d01=0,d02=0,d10=0,d11=0,d12=0,d20=0,d21=0,d22=0,vsum=0;
        DECL_VISIT(A_);
        DECL_VISIT(B_);

        int slots = 0, nextV = tid + 1024;
        const int vi0 = tid, vi1 = tid + 512;
        if (vi0 < T) {
            int part = (vi0 < pvLim) ? (int)claim[vi0] : -1;
            int pk = (part >= 0)
                   ? entS[(size_t)part * chunk4S + Sb[part] + (vi0 - Qb[part])]
                   : fetch_entry_bs(entS, Sb, Qb, chunk4S, vi0);
            LOAD_VISIT(A_, pk); DIAG_S(A_); slots |= 0x07;
        }
        if (vi1 < T) {
            int part = (vi1 < pvLim) ? (int)claim[vi1] : -1;
            int pk = (part >= 0)
                   ? entS[(size_t)part * chunk4S + Sb[part] + (vi1 - Qb[part])]
                   : fetch_entry_bs(entS, Sb, Qb, chunk4S, vi1);
            LOAD_VISIT(B_, pk); DIAG_S(B_); slots |= 0x38;
        }
        __syncthreads();   // pvt consumption done; claim loop may begin

        int p = 0;
        for (;;) {
            if (slots || nextV < T) flg[p] = 1;
            if (slots & 0x01) claim[A_k0] = (unsigned short)tid;
            if (slots & 0x02) claim[A_k1] = (unsigned short)tid;
            if (slots & 0x04) claim[A_k2] = (unsigned short)tid;
            if (slots & 0x08) claim[B_k0] = (unsigned short)tid;
            if (slots & 0x10) claim[B_k1] = (unsigned short)tid;
            if (slots & 0x20) claim[B_k2] = (unsigned short)tid;
            __syncthreads();
            if (!flg[p]) break;
            if (tid == 0) flg[p ^ 1] = 0;
            WIN_S(A_, 0, 0x01)
            WIN_S(A_, 1, 0x02)
            WIN_S(A_, 2, 0x04)
            WIN_S(B_, 0, 0x08)
            WIN_S(B_, 1, 0x10)
            WIN_S(B_, 2, 0x20)
            if (!slots && nextV < T) {      // rare tail (row > 1024 visits)
                int pk = fetch_entry_bs(entS, Sb, Qb, chunk4S, nextV);
                LOAD_VISIT(B_, pk); DIAG_S(B_);
                slots = 0x38; nextV += 512;
            }
            p ^= 1;
            __syncthreads();
        }

        // diagonal reduction
        d00=wave_reduce(d00); d01=wave_reduce(d01); d02=wave_reduce(d02);
        d10=wave_reduce(d10); d11=wave_reduce(d11); d12=wave_reduce(d12);
        d20=wave_reduce(d20); d21=wave_reduce(d21); d22=wave_reduce(d22);
        vsum=wave_reduce(vsum);
        if ((tid & 63) == 0) {
            int w = tid >> 6;
            dred[w*10+0]=d00; dred[w*10+1]=d01; dred[w*10+2]=d02;
            dred[w*10+3]=d10; dred[w*10+4]=d11; dred[w*10+5]=d12;
            dred[w*10+6]=d20; dred[w*10+7]=d21; dred[w*10+8]=d22;
            dred[w*10+9]=vsum;
        }
        __syncthreads();
        if (tid < 10) {
            float t_ = 0.f;
            for (int w = 0; w < 8; ++w) t_ += dred[w*10 + tid];
            dred[80 + tid] = t_;
        }
        __syncthreads();
        if (tid < 9) {
            int i = tid / 3, j = tid - 3 * i;
            val[i * n3 + 3 * r + j] += dred[80 + tid];
        }
        __syncthreads();

        // Ks rows 3r..3r+2: plane-major -> pure b128 copies
        int q = n3 >> 2;
        for (int k4 = tid; k4 < 3 * q; k4 += 512) {
            int i = (k4 >= q) + (k4 >= 2*q);
            int t4 = k4 - i * q;
            float4 w = ((const float4*)(val + i * n3))[t4];
            ((float4*)(Ks + (size_t)(3*r + i) * n3))[t4] = w;
        }
        // Ms rows: zeros + diagonal
        float diag = rho * 0.25f * dred[89];
        for (int k4 = tid; k4 < 3 * q; k4 += 512) {
            int i = (k4 >= q) + (k4 >= 2*q);
            int t4 = k4 - i * q;
            int dcol = 3*r + i;
            int base = t4 << 2;
            float4 w;
            w.x = (base + 0 == dcol) ? diag : 0.f;
            w.y = (base + 1 == dcol) ? diag : 0.f;
            w.z = (base + 2 == dcol) ? diag : 0.f;
            w.w = (base + 3 == dcol) ? diag : 0.f;
            ((float4*)(Ms + (size_t)(3*r + i) * n3))[t4] = w;
        }
    } else {
        // ================= fluid =================
        const int4* elems4 = fe;
        float* val = (float*)smem;                               // 2n (K plane, M plane)
        unsigned short* claim = (unsigned short*)(val + 2 * n);  // n
        int* Sb = (int*)(claim + n);                             // 256
        int* Qb = Sb + 256;                                      // 257
        float* dred = (float*)(Qb + 257);                        // 18
        int* flg = (int*)(dred + 18);                            // 2

        {
            float4* v = (float4*)val;
            int cnt = (2 * n) >> 2;
            for (int k = tid; k < cnt; k += 512) v[k] = make_float4(0.f,0.f,0.f,0.f);
        }
        if (tid < 256) {
            int s0 = PF[(size_t)r * G_PART + tid];
            int e0 = PF[(size_t)(r + 1) * G_PART + tid];
            Sb[tid] = s0;
            Qb[tid] = e0 - s0;
        }
        if (tid == 0) { flg[0] = 0; flg[1] = 0; }
        __syncthreads();
        if (tid < 64) {
            int c0 = Qb[4*tid], c1 = Qb[4*tid+1], c2 = Qb[4*tid+2], c3 = Qb[4*tid+3];
            int s = c0 + c1 + c2 + c3;
            int x = s;
#pragma unroll
            for (int d = 1; d < 64; d <<= 1) {
                int y = __shfl_up(x, d, 64);
                if (tid >= d) x += y;
            }
            int ex = x - s;
            Qb[4*tid] = ex; Qb[4*tid+1] = ex + c0;
            Qb[4*tid+2] = ex + c0 + c1; Qb[4*tid+3] = ex + c0 + c1 + c2;
            if (tid == 63) Qb[256] = ex + s;
        }
        __syncthreads();
        const int T = Qb[256];
        const int pvLim = min(T, n);

        if (tid < 256) {
            int v0 = Qb[tid], v1 = min(Qb[tid + 1], pvLim);
            for (int v = v0; v < v1; ++v) claim[v] = (unsigned short)tid;
        }
        __syncthreads();

        float dK = 0.f, dM = 0.f;
        DECL_VISIT(A_);
        DECL_VISIT(B_);

        int slots = 0, nextV = tid + 1024;
        const int vi0 = tid, vi1 = tid + 512;
        if (vi0 < T) {
            int part = (vi0 < pvLim) ? (int)claim[vi0] : -1;
            int pk = (part >= 0)
                   ? entF[(size_t)part * chunk4F + Sb[part] + (vi0 - Qb[part])]
                   : fetch_entry_bs(entF, Sb, Qb, chunk4F, vi0);
            LOAD_VISIT(A_, pk); DIAG_F(A_); slots |= 0x07;
        }
        if (vi1 < T) {
            int part = (vi1 < pvLim) ? (int)claim[vi1] : -1;
            int pk = (part >= 0)
                   ? entF[(size_t)part * chunk4F + Sb[part] + (vi1 - Qb[part])]
                   : fetch_entry_bs(entF, Sb, Qb, chunk4F, vi1);
            LOAD_VISIT(B_, pk); DIAG_F(B_); slots |= 0x38;
        }
        __syncthreads();

        int p = 0;
        for (;;) {
            if (slots || nextV < T) flg[p] = 1;
            if (slots & 0x01) claim[A_k0] = (unsigned short)tid;
            if (slots & 0x02) claim[A_k1] = (unsigned short)tid;
            if (slots & 0x04) claim[A_k2] = (unsigned short)tid;
            if (slots & 0x08) claim[B_k0] = (unsigned short)tid;
            if (slots & 0x10) claim[B_k1] = (unsigned short)tid;
            if (slots & 0x20) claim[B_k2] = (unsigned short)tid;
            __syncthreads();
            if (!flg[p]) break;
            if (tid == 0) flg[p ^ 1] = 0;
            WIN_F(A_, 0, 0x01)
            WIN_F(A_, 1, 0x02)
            WIN_F(A_, 2, 0x04)
            WIN_F(B_, 0, 0x08)
            WIN_F(B_, 1, 0x10)
            WIN_F(B_, 2, 0x20)
            if (!slots && nextV < T) {
                int pk = fetch_entry_bs(entF, Sb, Qb, chunk4F, nextV);
                LOAD_VISIT(B_, pk); DIAG_F(B_);
                slots = 0x38; nextV += 512;
            }
            p ^= 1;
            __syncthreads();
        }

        dK = wave_reduce(dK);
        dM = wave_reduce(dM);
        if ((tid & 63) == 0) { int w = tid >> 6; dred[w*2+0] = dK; dred[w*2+1] = dM; }
        __syncthreads();
        if (tid < 2) {
            float t_ = 0.f;
            for (int w = 0; w < 8; ++w) t_ += dred[w*2 + tid];
            dred[16 + tid] = t_;
        }
        __syncthreads();
        if (tid == 0) { val[r] += dred[16]; val[n + r] += dred[17]; }
        __syncthreads();

        size_t rowoff = (size_t)r * n;
        int qf = n >> 2;
        float4* K4 = (float4*)(Kf + rowoff);
        float4* M4 = (float4*)(Mf + rowoff);
        for (int c4 = tid; c4 < qf; c4 += 512) {
            K4[c4] = ((const float4*)val)[c4];
            M4[c4] = ((const float4*)(val + n))[c4];
        }
    }
}

// --------------------------- fallback scatter path ---------------------------
__device__ __forceinline__ void tet_grads_d(const float* __restrict__ nodes,
                                            const int* ni, double g[4][3], double& vol)
{
    double p[4][3];
#pragma unroll
    for (int a = 0; a < 4; ++a) {
        const float* q = nodes + 3ll * ni[a];
        p[a][0] = (double)q[0]; p[a][1] = (double)q[1]; p[a][2] = (double)q[2];
    }
    double r1[3], r2[3], r3[3];
#pragma unroll
    for (int k = 0; k < 3; ++k) {
        r1[k] = p[1][k] - p[0][k];
        r2[k] = p[2][k] - p[0][k];
        r3[k] = p[3][k] - p[0][k];
    }
    double c23[3] = { r2[1]*r3[2]-r2[2]*r3[1], r2[2]*r3[0]-r2[0]*r3[2], r2[0]*r3[1]-r2[1]*r3[0] };
    double det = r1[0]*c23[0] + r1[1]*c23[1] + r1[2]*c23[2];
    double inv = 1.0 / det;
    double c31[3] = { r3[1]*r1[2]-r3[2]*r1[1], r3[2]*r1[0]-r3[0]*r1[2], r3[0]*r1[1]-r3[1]*r1[0] };
    double c12[3] = { r1[1]*r2[2]-r1[2]*r2[1], r1[2]*r2[0]-r1[0]*r2[2], r1[0]*r2[1]-r1[1]*r2[0] };
#pragma unroll
    for (int k = 0; k < 3; ++k) {
        g[1][k] = c23[k]*inv; g[2][k] = c31[k]*inv; g[3][k] = c12[k]*inv;
        g[0][k] = -(g[1][k] + g[2][k] + g[3][k]);
    }
    vol = fabs(det) / 6.0;
}

__global__ void __launch_bounds__(256)
fluid_assemble(const float* __restrict__ nodes, const int* __restrict__ elems,
               float* __restrict__ Kf, float* __restrict__ Mf, int nelem, int n)
{
    int e = blockIdx.x * blockDim.x + threadIdx.x;
    if (e >= nelem) return;
    const int4 nd = *reinterpret_cast<const int4*>(elems + 4ll * e);
    int ni[4] = { nd.x, nd.y, nd.z, nd.w };
    double g[4][3], vol;
    tet_grads_d(nodes, ni, g, vol);
#pragma unroll
    for (int a = 0; a < 4; ++a) {
        long long rowoff = (long long)ni[a] * n;
#pragma unroll
        for (int b = 0; b < 4; ++b) {
            double kv = vol * (g[a][0]*g[b][0] + g[a][1]*g[b][1] + g[a][2]*g[b][2]);
            double mv = vol * (a == b ? 0.3 : 0.1);
            atomicAdd(Kf + rowoff + ni[b], (float)kv);
            atomicAdd(Mf + rowoff + ni[b], (float)mv);
        }
    }
}

__global__ void __launch_bounds__(256)
solid_assemble(const float* __restrict__ nodes, const int* __restrict__ elems,
               float* __restrict__ Ks, float* __restrict__ Ms,
               const float* __restrict__ E_p, const float* __restrict__ nu_p,
               const float* __restrict__ rho_p, int nelem, int n3)
{
    int e = blockIdx.x * blockDim.x + threadIdx.x;
    if (e >= nelem) return;
    double E = (double)*E_p, nu = (double)*nu_p, rho = (double)*rho_p;
    double coeff = E / ((1.0 + nu) * (1.0 - 2.0 * nu));
    double lam = coeff * nu, mu = coeff * (1.0 - 2.0 * nu) * 0.5;
    const int4 nd = *reinterpret_cast<const int4*>(elems + 4ll * e);
    int ni[4] = { nd.x, nd.y, nd.z, nd.w };
    double g[4][3], vol;
    tet_grads_d(nodes, ni, g, vol);
    double lv = lam * vol, mv = mu * vol;
#pragma unroll
    for (int a = 0; a < 4; ++a) {
        long long row0 = 3ll * ni[a];
#pragma unroll
        for (int b = 0; b < 4; ++b) {
            long long col0 = 3ll * ni[b];
            double gg = g[a][0]*g[b][0] + g[a][1]*g[b][1] + g[a][2]*g[b][2];
#pragma unroll
            for (int i = 0; i < 3; ++i) {
                float* rowp = Ks + (row0 + i) * (long long)n3 + col0;
#pragma unroll
                for (int j = 0; j < 3; ++j) {
                    double val = lv * g[a][i] * g[b][j] + mv * g[a][j] * g[b][i];
                    if (i == j) val += mv * gg;
                    atomicAdd(rowp + j, (float)val);
                }
            }
        }
        float mval = (float)(rho * vol * 0.25);
#pragma unroll
        for (int i = 0; i < 3; ++i) {
            long long d = row0 + i;
            atomicAdd(Ms + d * (long long)n3 + d, mval);
        }
    }
}

// ---------------------------------------------------------------------------
extern "C" void kernel_launch(void* const* d_in, const int* in_sizes, int n_in,
                              void* d_out, int out_size, void* d_ws, size_t ws_size,
                              hipStream_t stream)
{
    const float* nodes = (const float*)d_in[0];
    const int*   fe    = (const int*)d_in[1];
    const int*   se    = (const int*)d_in[2];
    const float* E_p   = (const float*)d_in[3];
    const float* nu_p  = (const float*)d_in[4];
    const float* rho_p = (const float*)d_in[5];

    const int n  = in_sizes[0] / 3;
    const int nf = in_sizes[1] / 4;
    const int ns = in_sizes[2] / 4;
    const int n3 = 3 * n;

    float* out = (float*)d_out;
    float* Kf = out;
    float* Mf = Kf + (size_t)n * n;
    float* Ks = Mf + (size_t)n * n;
    float* Ms = Ks + (size_t)n3 * n3;

    const int chunkF = (nf + G_PART - 1) / G_PART;
    const int chunkS = (ns + G_PART - 1) / G_PART;

    size_t pos = 0;
    auto take = [&](size_t bytes) {
        size_t p = pos;
        pos = (pos + bytes + 255) & ~(size_t)255;
        return p;
    };
    size_t entF_o = take((size_t)4 * chunkF * G_PART * 4);
    size_t entS_o = take((size_t)4 * chunkS * G_PART * 4);
    size_t PF_o   = take((size_t)(n + 1) * G_PART * 4);
    size_t PS_o   = take((size_t)(n + 1) * G_PART * 4);

    size_t gatherLds = (size_t)9 * n * 4 + (size_t)n * 2 + (256 + 257) * 4 + 90 * 4 + 8;
    size_t indexLds  = (size_t)(n + 256) * 4;
    bool gather_ok = (pos <= ws_size) && ((n & 3) == 0) && (n <= 65535) &&
                     (gatherLds <= 80 * 1024) && (indexLds <= 64 * 1024);

    const int bs = 256;

    if (!gather_ok) {
        hipMemsetAsync(d_out, 0, (size_t)out_size * sizeof(float), stream);
        fluid_assemble<<<(nf + bs - 1) / bs, bs, 0, stream>>>(nodes, fe, Kf, Mf, nf, n);
        solid_assemble<<<(ns + bs - 1) / bs, bs, 0, stream>>>(nodes, se, Ks, Ms,
                                                              E_p, nu_p, rho_p, ns, n3);
        return;
    }

    char* ws = (char*)d_ws;
    int* entF = (int*)(ws + entF_o);
    int* entS = (int*)(ws + entS_o);
    int* PF   = (int*)(ws + PF_o);
    int* PS   = (int*)(ws + PS_o);

    const int4* fe4 = (const int4*)fe;
    const int4* se4 = (const int4*)se;

    index_build<<<2 * G_PART, bs, indexLds, stream>>>(fe4, se4, entF, entS, PF, PS,
                                                      nf, ns, n, chunkF, chunkS);
    fused_gather<<<2 * n, 512, gatherLds, stream>>>(entF, PF, entS, PS,
                                                    fe4, se4, nodes,
                                                    Kf, Mf, Ks, Ms,
                                                    E_p, nu_p, rho_p, n, n3,
                                                    4 * chunkF, 4 * chunkS);
}

// Round 9
// 208.321 us; speedup vs baseline: 1.0918x; 1.0918x over previous
//
#include <hip/hip_runtime.h>

// ---------------------------------------------------------------------------
// CoupledFEMSolver — fused gather assembly v4.
//   * index_build: per-partition LDS hist -> block scan -> transposed prefix
//     P2[node][partition] -> partition-contiguous SELF-CONTAINED int4 entries
//     {n0, n1, n2, n3 | (a<<12)}  (no elem indirection in the gather).
//   * fused_gather: coalesced P2 prologue; Qb wave-scan; O(1) visit->partition
//     table (pvt, reuses claim buf); fully prefetched visits from coalesced
//     16B entries + L1-resident nodes; SINGLE-claim arbitrated plain-write
//     LDS accumulation (r7 loop, proven); plane-major accumulators ->
//     contiguous b128 stores; diagonal in registers; M_s written inline.
//
// Geometry per tet (double math; K entries ~ 1/det reach ~1e14):
//   det = r1.(r2 x r3); g1=(r2xr3)/det, g2=(r3xr1)/det, g3=(r1xr2)/det,
//   g0=-(g1+g2+g3); vol=|det|/6
// Fluid:  K_e[a][b] = vol*(ga.gb); M_e[a][b] = vol*(a==b ? .3 : .1)
// Solid:  K block (a,b) entry (i,j) =
//   vol*(lam*ga_i*gb_j + mu*ga_j*gb_i + (i==j)*mu*(ga.gb));
//   M_s diagonal only: rho*vol/4 per dof.
// ---------------------------------------------------------------------------

#define G_PART 256

__device__ __forceinline__ float sel4(float x0, float x1, float x2, float x3, int a) {
    float r = x0;
    r = (a == 1) ? x1 : r;
    r = (a == 2) ? x2 : r;
    r = (a == 3) ? x3 : r;
    return r;
}
__device__ __forceinline__ int sel4i(int x0, int x1, int x2, int x3, int a) {
    int r = x0;
    r = (a == 1) ? x1 : r;
    r = (a == 2) ? x2 : r;
    r = (a == 3) ? x3 : r;
    return r;
}

__device__ __forceinline__ float wave_reduce(float v) {
#pragma unroll
    for (int m = 1; m < 64; m <<= 1) v += __shfl_xor(v, m, 64);
    return v;
}

// double-precision tet geometry -> f32 gradients g1..g3 and volume
__device__ __forceinline__ void tet_geom_f(const float* __restrict__ nodes,
                                           int n0, int n1, int n2, int n3_,
                                           float& gx1, float& gy1, float& gz1,
                                           float& gx2, float& gy2, float& gz2,
                                           float& gx3, float& gy3, float& gz3,
                                           float& volf)
{
    const float* q0 = nodes + 3ll * n0;
    const float* q1 = nodes + 3ll * n1;
    const float* q2 = nodes + 3ll * n2;
    const float* q3 = nodes + 3ll * n3_;
    double p0x = q0[0], p0y = q0[1], p0z = q0[2];
    double r1x = (double)q1[0] - p0x, r1y = (double)q1[1] - p0y, r1z = (double)q1[2] - p0z;
    double r2x = (double)q2[0] - p0x, r2y = (double)q2[1] - p0y, r2z = (double)q2[2] - p0z;
    double r3x = (double)q3[0] - p0x, r3y = (double)q3[1] - p0y, r3z = (double)q3[2] - p0z;
    double c23x = r2y*r3z - r2z*r3y, c23y = r2z*r3x - r2x*r3z, c23z = r2x*r3y - r2y*r3x;
    double det = r1x*c23x + r1y*c23y + r1z*c23z;
    double inv = 1.0 / det;
    double c31x = r3y*r1z - r3z*r1y, c31y = r3z*r1x - r3x*r1z, c31z = r3x*r1y - r3y*r1x;
    double c12x = r1y*r2z - r1z*r2y, c12y = r1z*r2x - r1x*r2z, c12z = r1x*r2y - r1y*r2x;
    gx1 = (float)(c23x*inv); gy1 = (float)(c23y*inv); gz1 = (float)(c23z*inv);
    gx2 = (float)(c31x*inv); gy2 = (float)(c31y*inv); gz2 = (float)(c31z*inv);
    gx3 = (float)(c12x*inv); gy3 = (float)(c12y*inv); gz3 = (float)(c12z*inv);
    volf = (float)(fabs(det) / 6.0);
}

// tail-only: 8-step bisection over Qb prefix (rare rows with >1024 visits)
__device__ __forceinline__ int4 fetch_entry_bs(const int4* __restrict__ ent,
                                               const int* __restrict__ Sb,
                                               const int* __restrict__ Qb,
                                               int chunk4, int v)
{
    int lo = 0, hi = 255;
#pragma unroll
    for (int it = 0; it < 8; ++it) {
        int mid = (lo + hi + 1) >> 1;
        bool ge = (Qb[mid] <= v);
        lo = ge ? mid : lo;
        hi = ge ? hi : mid - 1;
    }
    return ent[(size_t)lo * chunk4 + Sb[lo] + (v - Qb[lo])];
}

// named-register visit state
#define DECL_VISIT(P) \
    float P##gx0=0,P##gx1=0,P##gx2=0,P##gx3=0, P##gy0=0,P##gy1=0,P##gy2=0,P##gy3=0, \
          P##gz0=0,P##gz1=0,P##gz2=0,P##gz3=0, P##vol=0, P##ga0=0,P##ga1=0,P##ga2=0; \
    int P##a=0, P##c0=0,P##c1=0,P##c2=0,P##c3=0;

#define LOAD_VISIT(P, en_) do { \
    int ndw_ = (en_).w & 0xFFF; P##a = (en_).w >> 12; \
    P##c0 = (en_).x; P##c1 = (en_).y; P##c2 = (en_).z; P##c3 = ndw_; \
    tet_geom_f(nodes, P##c0, P##c1, P##c2, P##c3, \
        P##gx1,P##gy1,P##gz1, P##gx2,P##gy2,P##gz2, P##gx3,P##gy3,P##gz3, P##vol); \
    P##gx0 = -(P##gx1+P##gx2+P##gx3); \
    P##gy0 = -(P##gy1+P##gy2+P##gy3); \
    P##gz0 = -(P##gz1+P##gz2+P##gz3); \
    P##ga0 = sel4(P##gx0,P##gx1,P##gx2,P##gx3,P##a); \
    P##ga1 = sel4(P##gy0,P##gy1,P##gy2,P##gy3,P##a); \
    P##ga2 = sel4(P##gz0,P##gz1,P##gz2,P##gz3,P##a); \
} while (0)

#define DIAG_S(P) do { \
    float lv_ = lam*P##vol, mv_ = mu*P##vol, lm_ = lv_+mv_; \
    float mgg_ = mv_*(P##ga0*P##ga0 + P##ga1*P##ga1 + P##ga2*P##ga2); \
    d00 += lm_*P##ga0*P##ga0 + mgg_; d01 += lm_*P##ga0*P##ga1;        d02 += lm_*P##ga0*P##ga2; \
    d10 += lm_*P##ga1*P##ga0;        d11 += lm_*P##ga1*P##ga1 + mgg_; d12 += lm_*P##ga1*P##ga2; \
    d20 += lm_*P##ga2*P##ga0;        d21 += lm_*P##ga2*P##ga1;        d22 += lm_*P##ga2*P##ga2 + mgg_; \
    vsum += P##vol; } while (0)

#define DIAG_F(P) do { \
    dK += P##vol*(P##ga0*P##ga0 + P##ga1*P##ga1 + P##ga2*P##ga2); \
    dM += P##vol*0.3f; } while (0)

#define PAIR_S(P, b_) do { \
    float gb0_ = sel4(P##gx0,P##gx1,P##gx2,P##gx3,b_); \
    float gb1_ = sel4(P##gy0,P##gy1,P##gy2,P##gy3,b_); \
    float gb2_ = sel4(P##gz0,P##gz1,P##gz2,P##gz3,b_); \
    col = sel4i(P##c0,P##c1,P##c2,P##c3,b_); \
    float lv_ = lam*P##vol, mv_ = mu*P##vol; \
    float la0_ = lv_*P##ga0, la1_ = lv_*P##ga1, la2_ = lv_*P##ga2; \
    float ma0_ = mv_*P##ga0, ma1_ = mv_*P##ga1, ma2_ = mv_*P##ga2; \
    float mgg_ = mv_*(P##ga0*gb0_ + P##ga1*gb1_ + P##ga2*gb2_); \
    v00 = la0_*gb0_ + ma0_*gb0_ + mgg_; v01 = la0_*gb1_ + ma1_*gb0_; v02 = la0_*gb2_ + ma2_*gb0_; \
    v10 = la1_*gb0_ + ma0_*gb1_; v11 = la1_*gb1_ + ma1_*gb1_ + mgg_; v12 = la1_*gb2_ + ma2_*gb1_; \
    v20 = la2_*gb0_ + ma0_*gb2_; v21 = la2_*gb1_ + ma1_*gb2_; v22 = la2_*gb2_ + ma2_*gb2_ + mgg_; \
} while (0)

#define PAIR_F(P, b_) do { \
    float gb0_ = sel4(P##gx0,P##gx1,P##gx2,P##gx3,b_); \
    float gb1_ = sel4(P##gy0,P##gy1,P##gy2,P##gy3,b_); \
    float gb2_ = sel4(P##gz0,P##gz1,P##gz2,P##gz3,b_); \
    col = sel4i(P##c0,P##c1,P##c2,P##c3,b_); \
    vK = P##vol*(P##ga0*gb0_ + P##ga1*gb1_ + P##ga2*gb2_); \
    vM = P##vol*0.1f; \
} while (0)

// ------------------- one-kernel partition-local index build ------------------
__global__ void __launch_bounds__(256)
index_build(const int4* __restrict__ fe, const int4* __restrict__ se,
            int4* __restrict__ entF, int4* __restrict__ entS,
            int* __restrict__ PF, int* __restrict__ PS,
            int nf, int ns, int n, int chunkF, int chunkS)
{
    extern __shared__ int h[];            // n + 256
    int* wsum = h + n;
    const bool solid = blockIdx.x >= G_PART;
    const int b = solid ? blockIdx.x - G_PART : blockIdx.x;
    const int4* elems = solid ? se : fe;
    const int nelem = solid ? ns : nf;
    const int chunk = solid ? chunkS : chunkF;
    int* P2 = solid ? PS : PF;            // layout: P2[node][partition]
    int4* entries = (solid ? entS : entF) + (size_t)b * 4 * chunk;

    const int t = threadIdx.x;
    const int beg = b * chunk, end = min(nelem, beg + chunk);

    for (int i = t; i < n; i += 256) h[i] = 0;
    __syncthreads();
    for (int e = beg + t; e < end; e += 256) {
        int4 nd = elems[e];
        atomicAdd(&h[nd.x], 1);
        atomicAdd(&h[nd.y], 1);
        atomicAdd(&h[nd.z], 1);
        atomicAdd(&h[nd.w], 1);
    }
    __syncthreads();

    // block exclusive scan of h[0..n)
    const int cs = (n + 255) / 256;
    const int base = t * cs;
    int s = 0;
    for (int k = 0; k < cs; ++k) {
        int i = base + k;
        if (i < n) s += h[i];
    }
    wsum[t] = s;
    __syncthreads();
    for (int d = 1; d < 256; d <<= 1) {
        int v = (t >= d) ? wsum[t - d] : 0;
        __syncthreads();
        wsum[t] += v;
        __syncthreads();
    }
    int run = (t == 0) ? 0 : wsum[t - 1];
    for (int k = 0; k < cs; ++k) {
        int i = base + k;
        if (i < n) {
            int c = h[i]; h[i] = run;
            P2[(size_t)i * G_PART + b] = run;
            run += c;
        }
    }
    if (t == 255) P2[(size_t)n * G_PART + b] = wsum[255];
    __syncthreads();

    // place SELF-CONTAINED entries (h[] now holds cursors = prefix)
    for (int e = beg + t; e < end; e += 256) {
        int4 nd = elems[e];
        int p;
        p = atomicAdd(&h[nd.x], 1); entries[p] = make_int4(nd.x, nd.y, nd.z, nd.w);
        p = atomicAdd(&h[nd.y], 1); entries[p] = make_int4(nd.x, nd.y, nd.z, nd.w | (1<<12));
        p = atomicAdd(&h[nd.z], 1); entries[p] = make_int4(nd.x, nd.y, nd.z, nd.w | (2<<12));
        p = atomicAdd(&h[nd.w], 1); entries[p] = make_int4(nd.x, nd.y, nd.z, nd.w | (3<<12));
    }
}

// ------------------------------ fused gather --------------------------------
// blocks [0,n): solid rows; [n,2n): fluid rows.
__global__ void __launch_bounds__(512, 4)
fused_gather(const int4* __restrict__ entF, const int* __restrict__ PF,
             const int4* __restrict__ entS, const int* __restrict__ PS,
             const float* __restrict__ nodes,
             float* __restrict__ Kf, float* __restrict__ Mf,
             float* __restrict__ Ks, float* __restrict__ Ms,
             const float* __restrict__ E_p, const float* __restrict__ nu_p,
             const float* __restrict__ rho_p, int n, int n3,
             int chunk4F, int chunk4S)
{
    extern __shared__ unsigned char smem[];
    const int tid = threadIdx.x;
    const int bid = blockIdx.x;

    if (bid < n) {
        // ================= solid =================
        const int r = bid;
        float* val = (float*)smem;                               // 9n (3 planes of n3)
        unsigned short* claim = (unsigned short*)(val + 9 * n);  // n (pvt in prologue)
        int* Sb = (int*)(claim + n);                             // 256
        int* Qb = Sb + 256;                                      // 257
        float* dred = (float*)(Qb + 257);                        // 90

        {
            float4* v = (float4*)val;
            int cnt = (9 * n) >> 2;
            for (int k = tid; k < cnt; k += 512) v[k] = make_float4(0.f,0.f,0.f,0.f);
        }
        if (tid < 256) {
            int s0 = PS[(size_t)r * G_PART + tid];
            int e0 = PS[(size_t)(r + 1) * G_PART + tid];
            Sb[tid] = s0;
            Qb[tid] = e0 - s0;     // counts; scanned below
        }
        __syncthreads();
        if (tid < 64) {
            int c0 = Qb[4*tid], c1 = Qb[4*tid+1], c2 = Qb[4*tid+2], c3 = Qb[4*tid+3];
            int s = c0 + c1 + c2 + c3;
            int x = s;
#pragma unroll
            for (int d = 1; d < 64; d <<= 1) {
                int y = __shfl_up(x, d, 64);
                if (tid >= d) x += y;
            }
            int ex = x - s;
            Qb[4*tid] = ex; Qb[4*tid+1] = ex + c0;
            Qb[4*tid+2] = ex + c0 + c1; Qb[4*tid+3] = ex + c0 + c1 + c2;
            if (tid == 63) Qb[256] = ex + s;
        }
        __syncthreads();
        const int T = Qb[256];
        const int pvLim = min(T, n);

        // O(1) visit->partition table in claim buffer (consumed before loop)
        if (tid < 256) {
            int v0 = Qb[tid], v1 = min(Qb[tid + 1], pvLim);
            for (int v = v0; v < v1; ++v) claim[v] = (unsigned short)tid;
        }
        __syncthreads();

        float E = *E_p, nu = *nu_p, rho = *rho_p;
        float coeff = E / ((1.f + nu) * (1.f - 2.f * nu));
        float lam = coeff * nu;
        float mu  = coeff * (1.f - 2.f * nu) * 0.5f;

        float d00=0,d01=0,d02=0,d10=0,d11=0,d12=0,d20=0,d21=0,d22=0,vsum=0;
        DECL_VISIT(A_);
        DECL_VISIT(B_);

        bool pending = false, validB = false;
        int s, col = 0, nextV = tid + 1024;
        float v00=0,v01=0,v02=0,v10=0,v11=0,v12=0,v20=0,v21=0,v22=0;

        const int vi0 = tid, vi1 = tid + 512;
        if (vi0 < T) {
            int part = (int)claim[vi0];
            int4 en = entS[(size_t)part * chunk4S + Sb[part] + (vi0 - Qb[part])];
            LOAD_VISIT(A_, en); DIAG_S(A_); s = 0;
        } else s = 6;
        if (vi1 < T) {
            int4 en = (vi1 < pvLim)
                ? entS[(size_t)claim[vi1] * chunk4S + Sb[claim[vi1]] + (vi1 - Qb[claim[vi1]])]
                : fetch_entry_bs(entS, Sb, Qb, chunk4S, vi1);
            LOAD_VISIT(B_, en); DIAG_S(B_); validB = true;
        }

        auto advanceS = [&]() {
            while (!pending) {
                if (s >= 6 || (s >= 3 && !validB)) {
                    if (nextV >= T) return;
                    int4 en = fetch_entry_bs(entS, Sb, Qb, chunk4S, nextV);  // rare tail
                    LOAD_VISIT(B_, en); DIAG_S(B_);
                    validB = true; nextV += 512; s = 3;
                }
                if (s < 3) { int t_ = s;     int b_ = t_ + (t_ >= A_a ? 1 : 0); PAIR_S(A_, b_); }
                else       { int t_ = s - 3; int b_ = t_ + (t_ >= B_a ? 1 : 0); PAIR_S(B_, b_); }
                ++s; pending = true;
            }
        };

        advanceS();
        __syncthreads();   // pvt consumption done; claim array reusable

        int live = __syncthreads_count(pending ? 1 : 0);
        while (live) {
            if (pending) claim[col] = (unsigned short)tid;
            __syncthreads();
            if (pending && claim[col] == (unsigned short)tid) {
                float* p0 = val + 3 * col;
                float* p1 = p0 + n3;
                float* p2 = p1 + n3;
                p0[0]+=v00; p0[1]+=v01; p0[2]+=v02;
                p1[0]+=v10; p1[1]+=v11; p1[2]+=v12;
                p2[0]+=v20; p2[1]+=v21; p2[2]+=v22;
                pending = false;
                advanceS();
            }
            live = __syncthreads_count(pending ? 1 : 0);
        }

        // diagonal reduction
        d00=wave_reduce(d00); d01=wave_reduce(d01); d02=wave_reduce(d02);
        d10=wave_reduce(d10); d11=wave_reduce(d11); d12=wave_reduce(d12);
        d20=wave_reduce(d20); d21=wave_reduce(d21); d22=wave_reduce(d22);
        vsum=wave_reduce(vsum);
        if ((tid & 63) == 0) {
            int w = tid >> 6;
            dred[w*10+0]=d00; dred[w*10+1]=d01; dred[w*10+2]=d02;
            dred[w*10+3]=d10; dred[w*10+4]=d11; dred[w*10+5]=d12;
            dred[w*10+6]=d20; dred[w*10+7]=d21; dred[w*10+8]=d22;
            dred[w*10+9]=vsum;
        }
        __syncthreads();
        if (tid < 10) {
            float t_ = 0.f;
            for (int w = 0; w < 8; ++w) t_ += dred[w*10 + tid];
            dred[80 + tid] = t_;
        }
        __syncthreads();
        if (tid < 9) {
            int i = tid / 3, j = tid - 3 * i;
            val[i * n3 + 3 * r + j] += dred[80 + tid];
        }
        __syncthreads();

        // Ks rows 3r..3r+2: plane-major -> pure b128 copies
        int q = n3 >> 2;
        for (int k4 = tid; k4 < 3 * q; k4 += 512) {
            int i = (k4 >= q) + (k4 >= 2*q);
            int t4 = k4 - i * q;
            float4 w = ((const float4*)(val + i * n3))[t4];
            ((float4*)(Ks + (size_t)(3*r + i) * n3))[t4] = w;
        }
        // Ms rows: zeros + diagonal
        float diag = rho * 0.25f * dred[89];
        for (int k4 = tid; k4 < 3 * q; k4 += 512) {
            int i = (k4 >= q) + (k4 >= 2*q);
            int t4 = k4 - i * q;
            int dcol = 3*r + i;
            int base = t4 << 2;
            float4 w;
            w.x = (base + 0 == dcol) ? diag : 0.f;
            w.y = (base + 1 == dcol) ? diag : 0.f;
            w.z = (base + 2 == dcol) ? diag : 0.f;
            w.w = (base + 3 == dcol) ? diag : 0.f;
            ((float4*)(Ms + (size_t)(3*r + i) * n3))[t4] = w;
        }
    } else {
        // ================= fluid =================
        const int r = bid - n;
        float* val = (float*)smem;                               // 2n (K plane, M plane)
        unsigned short* claim = (unsigned short*)(val + 2 * n);  // n
        int* Sb = (int*)(claim + n);                             // 256
        int* Qb = Sb + 256;                                      // 257
        float* dred = (float*)(Qb + 257);                        // 18

        {
            float4* v = (float4*)val;
            int cnt = (2 * n) >> 2;
            for (int k = tid; k < cnt; k += 512) v[k] = make_float4(0.f,0.f,0.f,0.f);
        }
        if (tid < 256) {
            int s0 = PF[(size_t)r * G_PART + tid];
            int e0 = PF[(size_t)(r + 1) * G_PART + tid];
            Sb[tid] = s0;
            Qb[tid] = e0 - s0;
        }
        __syncthreads();
        if (tid < 64) {
            int c0 = Qb[4*tid], c1 = Qb[4*tid+1], c2 = Qb[4*tid+2], c3 = Qb[4*tid+3];
            int s = c0 + c1 + c2 + c3;
            int x = s;
#pragma unroll
            for (int d = 1; d < 64; d <<= 1) {
                int y = __shfl_up(x, d, 64);
                if (tid >= d) x += y;
            }
            int ex = x - s;
            Qb[4*tid] = ex; Qb[4*tid+1] = ex + c0;
            Qb[4*tid+2] = ex + c0 + c1; Qb[4*tid+3] = ex + c0 + c1 + c2;
            if (tid == 63) Qb[256] = ex + s;
        }
        __syncthreads();
        const int T = Qb[256];
        const int pvLim = min(T, n);

        if (tid < 256) {
            int v0 = Qb[tid], v1 = min(Qb[tid + 1], pvLim);
            for (int v = v0; v < v1; ++v) claim[v] = (unsigned short)tid;
        }
        __syncthreads();

        float dK = 0.f, dM = 0.f;
        DECL_VISIT(A_);
        DECL_VISIT(B_);

        bool pending = false, validB = false;
        int s, col = 0, nextV = tid + 1024;
        float vK = 0.f, vM = 0.f;

        const int vi0 = tid, vi1 = tid + 512;
        if (vi0 < T) {
            int part = (int)claim[vi0];
            int4 en = entF[(size_t)part * chunk4F + Sb[part] + (vi0 - Qb[part])];
            LOAD_VISIT(A_, en); DIAG_F(A_); s = 0;
        } else s = 6;
        if (vi1 < T) {
            int4 en = (vi1 < pvLim)
                ? entF[(size_t)claim[vi1] * chunk4F + Sb[claim[vi1]] + (vi1 - Qb[claim[vi1]])]
                : fetch_entry_bs(entF, Sb, Qb, chunk4F, vi1);
            LOAD_VISIT(B_, en); DIAG_F(B_); validB = true;
        }

        auto advanceF = [&]() {
            while (!pending) {
                if (s >= 6 || (s >= 3 && !validB)) {
                    if (nextV >= T) return;
                    int4 en = fetch_entry_bs(entF, Sb, Qb, chunk4F, nextV);
                    LOAD_VISIT(B_, en); DIAG_F(B_);
                    validB = true; nextV += 512; s = 3;
                }
                if (s < 3) { int t_ = s;     int b_ = t_ + (t_ >= A_a ? 1 : 0); PAIR_F(A_, b_); }
                else       { int t_ = s - 3; int b_ = t_ + (t_ >= B_a ? 1 : 0); PAIR_F(B_, b_); }
                ++s; pending = true;
            }
        };

        advanceF();
        __syncthreads();

        int live = __syncthreads_count(pending ? 1 : 0);
        while (live) {
            if (pending) claim[col] = (unsigned short)tid;
            __syncthreads();
            if (pending && claim[col] == (unsigned short)tid) {
                val[col]     += vK;
                val[n + col] += vM;
                pending = false;
                advanceF();
            }
            live = __syncthreads_count(pending ? 1 : 0);
        }

        dK = wave_reduce(dK);
        dM = wave_reduce(dM);
        if ((tid & 63) == 0) { int w = tid >> 6; dred[w*2+0] = dK; dred[w*2+1] = dM; }
        __syncthreads();
        if (tid < 2) {
            float t_ = 0.f;
            for (int w = 0; w < 8; ++w) t_ += dred[w*2 + tid];
            dred[16 + tid] = t_;
        }
        __syncthreads();
        if (tid == 0) { val[r] += dred[16]; val[n + r] += dred[17]; }
        __syncthreads();

        size_t rowoff = (size_t)r * n;
        int qf = n >> 2;
        float4* K4 = (float4*)(Kf + rowoff);
        float4* M4 = (float4*)(Mf + rowoff);
        for (int c4 = tid; c4 < qf; c4 += 512) {
            K4[c4] = ((const float4*)val)[c4];
            M4[c4] = ((const float4*)(val + n))[c4];
        }
    }
}

// --------------------------- fallback scatter path ---------------------------
__device__ __forceinline__ void tet_grads_d(const float* __restrict__ nodes,
                                            const int* ni, double g[4][3], double& vol)
{
    double p[4][3];
#pragma unroll
    for (int a = 0; a < 4; ++a) {
        const float* q = nodes + 3ll * ni[a];
        p[a][0] = (double)q[0]; p[a][1] = (double)q[1]; p[a][2] = (double)q[2];
    }
    double r1[3], r2[3], r3[3];
#pragma unroll
    for (int k = 0; k < 3; ++k) {
        r1[k] = p[1][k] - p[0][k];
        r2[k] = p[2][k] - p[0][k];
        r3[k] = p[3][k] - p[0][k];
    }
    double c23[3] = { r2[1]*r3[2]-r2[2]*r3[1], r2[2]*r3[0]-r2[0]*r3[2], r2[0]*r3[1]-r2[1]*r3[0] };
    double det = r1[0]*c23[0] + r1[1]*c23[1] + r1[2]*c23[2];
    double inv = 1.0 / det;
    double c31[3] = { r3[1]*r1[2]-r3[2]*r1[1], r3[2]*r1[0]-r3[0]*r1[2], r3[0]*r1[1]-r3[1]*r1[0] };
    double c12[3] = { r1[1]*r2[2]-r1[2]*r2[1], r1[2]*r2[0]-r1[0]*r2[2], r1[0]*r2[1]-r1[1]*r2[0] };
#pragma unroll
    for (int k = 0; k < 3; ++k) {
        g[1][k] = c23[k]*inv; g[2][k] = c31[k]*inv; g[3][k] = c12[k]*inv;
        g[0][k] = -(g[1][k] + g[2][k] + g[3][k]);
    }
    vol = fabs(det) / 6.0;
}

__global__ void __launch_bounds__(256)
fluid_assemble(const float* __restrict__ nodes, const int* __restrict__ elems,
               float* __restrict__ Kf, float* __restrict__ Mf, int nelem, int n)
{
    int e = blockIdx.x * blockDim.x + threadIdx.x;
    if (e >= nelem) return;
    const int4 nd = *reinterpret_cast<const int4*>(elems + 4ll * e);
    int ni[4] = { nd.x, nd.y, nd.z, nd.w };
    double g[4][3], vol;
    tet_grads_d(nodes, ni, g, vol);
#pragma unroll
    for (int a = 0; a < 4; ++a) {
        long long rowoff = (long long)ni[a] * n;
#pragma unroll
        for (int b = 0; b < 4; ++b) {
            double kv = vol * (g[a][0]*g[b][0] + g[a][1]*g[b][1] + g[a][2]*g[b][2]);
            double mv = vol * (a == b ? 0.3 : 0.1);
            atomicAdd(Kf + rowoff + ni[b], (float)kv);
            atomicAdd(Mf + rowoff + ni[b], (float)mv);
        }
    }
}

__global__ void __launch_bounds__(256)
solid_assemble(const float* __restrict__ nodes, const int* __restrict__ elems,
               float* __restrict__ Ks, float* __restrict__ Ms,
               const float* __restrict__ E_p, const float* __restrict__ nu_p,
               const float* __restrict__ rho_p, int nelem, int n3)
{
    int e = blockIdx.x * blockDim.x + threadIdx.x;
    if (e >= nelem) return;
    double E = (double)*E_p, nu = (double)*nu_p, rho = (double)*rho_p;
    double coeff = E / ((1.0 + nu) * (1.0 - 2.0 * nu));
    double lam = coeff * nu, mu = coeff * (1.0 - 2.0 * nu) * 0.5;
    const int4 nd = *reinterpret_cast<const int4*>(elems + 4ll * e);
    int ni[4] = { nd.x, nd.y, nd.z, nd.w };
    double g[4][3], vol;
    tet_grads_d(nodes, ni, g, vol);
    double lv = lam * vol, mv = mu * vol;
#pragma unroll
    for (int a = 0; a < 4; ++a) {
        long long row0 = 3ll * ni[a];
#pragma unroll
        for (int b = 0; b < 4; ++b) {
            long long col0 = 3ll * ni[b];
            double gg = g[a][0]*g[b][0] + g[a][1]*g[b][1] + g[a][2]*g[b][2];
#pragma unroll
            for (int i = 0; i < 3; ++i) {
                float* rowp = Ks + (row0 + i) * (long long)n3 + col0;
#pragma unroll
                for (int j = 0; j < 3; ++j) {
                    double val = lv * g[a][i] * g[b][j] + mv * g[a][j] * g[b][i];
                    if (i == j) val += mv * gg;
                    atomicAdd(rowp + j, (float)val);
                }
            }
        }
        float mval = (float)(rho * vol * 0.25);
#pragma unroll
        for (int i = 0; i < 3; ++i) {
            long long d = row0 + i;
            atomicAdd(Ms + d * (long long)n3 + d, mval);
        }
    }
}

// ---------------------------------------------------------------------------
extern "C" void kernel_launch(void* const* d_in, const int* in_sizes, int n_in,
                              void* d_out, int out_size, void* d_ws, size_t ws_size,
                              hipStream_t stream)
{
    const float* nodes = (const float*)d_in[0];
    const int*   fe    = (const int*)d_in[1];
    const int*   se    = (const int*)d_in[2];
    const float* E_p   = (const float*)d_in[3];
    const float* nu_p  = (const float*)d_in[4];
    const float* rho_p = (const float*)d_in[5];

    const int n  = in_sizes[0] / 3;
    const int nf = in_sizes[1] / 4;
    const int ns = in_sizes[2] / 4;
    const int n3 = 3 * n;

    float* out = (float*)d_out;
    float* Kf = out;
    float* Mf = Kf + (size_t)n * n;
    float* Ks = Mf + (size_t)n * n;
    float* Ms = Ks + (size_t)n3 * n3;

    const int chunkF = (nf + G_PART - 1) / G_PART;
    const int chunkS = (ns + G_PART - 1) / G_PART;

    size_t pos = 0;
    auto take = [&](size_t bytes) {
        size_t p = pos;
        pos = (pos + bytes + 255) & ~(size_t)255;
        return p;
    };
    size_t entF_o = take((size_t)4 * chunkF * G_PART * 16);
    size_t entS_o = take((size_t)4 * chunkS * G_PART * 16);
    size_t PF_o   = take((size_t)(n + 1) * G_PART * 4);
    size_t PS_o   = take((size_t)(n + 1) * G_PART * 4);

    size_t gatherLds = (size_t)9 * n * 4 + (size_t)n * 2 + (256 + 257) * 4 + 90 * 4;
    size_t indexLds  = (size_t)(n + 256) * 4;
    bool gather_ok = (pos <= ws_size) && ((n & 3) == 0) && (n <= 4095) &&
                     (gatherLds <= 80 * 1024) && (indexLds <= 64 * 1024);

    const int bs = 256;

    if (!gather_ok) {
        hipMemsetAsync(d_out, 0, (size_t)out_size * sizeof(float), stream);
        fluid_assemble<<<(nf + bs - 1) / bs, bs, 0, stream>>>(nodes, fe, Kf, Mf, nf, n);
        solid_assemble<<<(ns + bs - 1) / bs, bs, 0, stream>>>(nodes, se, Ks, Ms,
                                                              E_p, nu_p, rho_p, ns, n3);
        return;
    }

    char* ws = (char*)d_ws;
    int4* entF = (int4*)(ws + entF_o);
    int4* entS = (int4*)(ws + entS_o);
    int* PF    = (int*)(ws + PF_o);
    int* PS    = (int*)(ws + PS_o);

    const int4* fe4 = (const int4*)fe;
    const int4* se4 = (const int4*)se;

    index_build<<<2 * G_PART, bs, indexLds, stream>>>(fe4, se4, entF, entS, PF, PS,
                                                      nf, ns, n, chunkF, chunkS);
    fused_gather<<<2 * n, 512, gatherLds, stream>>>(entF, PF, entS, PS,
                                                    nodes,
                                                    Kf, Mf, Ks, Ms,
                                                    E_p, nu_p, rho_p, n, n3,
                                                    4 * chunkF, 4 * chunkS);
}